// Round 5
// baseline (495.377 us; speedup 1.0000x reference)
//
#include <hip/hip_runtime.h>
#include <hip/hip_bf16.h>

// Problem: B=512, GS=2048, PARAM=64, C=2, OGS=1024, PARAMO=64
//   x: (512, 2048, 64) f32, trafo: (128, 64) f32, out: (512, 1024, 64) f32
#define BATCH  512
#define GSZ    2048
#define PAR    64
#define OGS    1024
#define KDIM   128
#define NDIM   64

// ---------------------------------------------------------------------------
// Kernel 1: stable LSD radix sort (4 passes x 8 bits), descending-transformed
// f32 keys, payload = index. LSD stability == top_k tie semantics.
// (unchanged — passed round 2, absmax 0.0)
// ---------------------------------------------------------------------------
__global__ __launch_bounds__(1024) void radix_sort_kernel(
    const float* __restrict__ x, int* __restrict__ order) {
    __shared__ unsigned keyA[GSZ], payA[GSZ], keyB[GSZ], payB[GSZ];
    __shared__ unsigned hist[32][256];        // [chunk][digit]
    __shared__ unsigned totals[256], base[256], wtot[4];

    const int b = blockIdx.x;
    const int t = threadIdx.x;
    const int w = t >> 6, lane = t & 63;

    #pragma unroll
    for (int s = 0; s < 2; ++s) {
        int i = t + s * 1024;
        unsigned u = __float_as_uint(x[(size_t)b * GSZ * PAR + (size_t)i * PAR + (PAR - 1)]);
        u = (u & 0x80000000u) ? ~u : (u | 0x80000000u); // ascending monotonic
        keyA[i] = ~u;                                    // descending value
        payA[i] = (unsigned)i;
    }
    __syncthreads();

    for (int pass = 0; pass < 4; ++pass) {
        const int sh = pass * 8;
        unsigned* ksrc = (pass & 1) ? keyB : keyA;
        unsigned* psrc = (pass & 1) ? payB : payA;
        unsigned* kdst = (pass & 1) ? keyA : keyB;
        unsigned* pdst = (pass & 1) ? payA : payB;

        #pragma unroll
        for (int i = 0; i < 8; ++i) ((unsigned*)hist)[t + i * 1024] = 0u;
        __syncthreads();

        unsigned dreg[2], wreg[2];
        #pragma unroll
        for (int s = 0; s < 2; ++s) {
            int e = t + s * 1024;
            int chunk = w + s * 16;
            unsigned k = ksrc[e];
            unsigned dd = (k >> sh) & 255u;
            unsigned long long m = ~0ull;
            #pragma unroll
            for (int bit = 0; bit < 8; ++bit) {
                unsigned long long bb = __ballot((dd >> bit) & 1u);
                m &= ((dd >> bit) & 1u) ? bb : ~bb;
            }
            unsigned within = __builtin_amdgcn_mbcnt_hi(
                (unsigned)(m >> 32), __builtin_amdgcn_mbcnt_lo((unsigned)m, 0u));
            if (within == 0u) hist[chunk][dd] = (unsigned)__popcll(m);
            dreg[s] = dd; wreg[s] = within;
        }
        __syncthreads();

        if (t < 256) {
            unsigned run = 0;
            #pragma unroll
            for (int c = 0; c < 32; ++c) {
                unsigned v = hist[c][t];
                hist[c][t] = run;
                run += v;
            }
            totals[t] = run;
        }
        __syncthreads();

        unsigned v256 = 0, inc = 0;
        if (t < 256) {
            v256 = totals[t];
            inc = v256;
            #pragma unroll
            for (int off = 1; off < 64; off <<= 1) {
                unsigned n = __shfl_up(inc, off, 64);
                if (lane >= off) inc += n;
            }
            if (lane == 63) wtot[t >> 6] = inc;
        }
        __syncthreads();
        if (t < 256) {
            unsigned o = 0;
            #pragma unroll
            for (int j = 0; j < 4; ++j) if (j < (t >> 6)) o += wtot[j];
            base[t] = o + inc - v256;   // exclusive
        }
        __syncthreads();

        #pragma unroll
        for (int s = 0; s < 2; ++s) {
            int e = t + s * 1024;
            int chunk = w + s * 16;
            unsigned k = ksrc[e];
            unsigned p = psrc[e];
            unsigned dd = dreg[s];
            unsigned r = base[dd] + hist[chunk][dd] + wreg[s];
            if (pass == 3) {
                order[b * GSZ + (int)r] = (int)p;
            } else {
                kdst[r] = k; pdst[r] = p;
            }
        }
        __syncthreads();
    }
}

// ---------------------------------------------------------------------------
// Kernel 2 (v3): gather + GEMM, lane = output row, B via wave-uniform scalar
// loads from global (L1/L2-hot), 1 ds_read_b32 per k = 0.125 B/FMA LDS
// traffic; K-chunked (32) double-buffered staging, ONE barrier per chunk,
// register prefetch.
// Block 256 thr (4 waves), tile 128 rows x 64 cols.
// Wave w: rows (w&1)*64 + lane, cols (w>>1)*32 .. +31 (uniform -> s_load B).
// LDS Ash[2][32][128] = 32 KB -> 4-5 blocks/CU.
// Accumulation: k ascending per output (exact f32 match, absmax 0.0).
// ---------------------------------------------------------------------------
#define TM 128

__global__ __launch_bounds__(256) void gather_gemm_kernel(
    const float* __restrict__ x, const float* __restrict__ trafo,
    const int* __restrict__ order, float* __restrict__ out) {
    __shared__ float Ash[2][32][TM];   // 32 KB

    const int b    = blockIdx.x >> 3;
    const int tile = blockIdx.x & 7;
    const int g0   = tile * TM;
    const int t    = threadIdx.x;
    const int w    = t >> 6;
    const int lane = t & 63;
    const int row  = t & 127;          // staging: local xs-row
    const int fh   = t >> 7;           // staging: which 64B half of the chunk
    const int rbase = (w & 1) * 64;
    const int cbase = __builtin_amdgcn_readfirstlane((w >> 1) * 32);

    const float* xb = x + (size_t)b * GSZ * PAR;
    const int* ob   = order + b * GSZ + 2 * g0;
    const int s0 = ob[2 * row + 0];
    const int s1 = ob[2 * row + 1];

    #define STORE4(buf, v, i) { int k = fh * 16 + (i) * 4; \
        Ash[buf][k + 0][row] = (v).x; Ash[buf][k + 1][row] = (v).y; \
        Ash[buf][k + 2][row] = (v).z; Ash[buf][k + 3][row] = (v).w; }

    // ---- prologue: stage chunk 0 (src s0, cols [0,32)) ----
    {
        const float4* sp = (const float4*)(xb + (size_t)s0 * PAR) + fh * 4;
        float4 v0 = sp[0], v1 = sp[1], v2 = sp[2], v3 = sp[3];
        STORE4(0, v0, 0) STORE4(0, v1, 1) STORE4(0, v2, 2) STORE4(0, v3, 3)
    }
    __syncthreads();

    float acc[32];
    #pragma unroll
    for (int c = 0; c < 32; ++c) acc[c] = 0.0f;

    int cur = 0;
    for (int c = 0; c < 4; ++c) {
        // prefetch next chunk into registers (latency hides under compute)
        float4 p0, p1, p2, p3;
        if (c < 3) {
            const int cn = c + 1;
            const float* srow = xb + (size_t)((cn >> 1) ? s1 : s0) * PAR + (cn & 1) * 32;
            const float4* sp = (const float4*)srow + fh * 4;
            p0 = sp[0]; p1 = sp[1]; p2 = sp[2]; p3 = sp[3];
        }

        // compute 32 k-steps: A broadcast-row from LDS, B scalar from global
        const float* trb = trafo + (size_t)(c * 32) * NDIM + cbase;
        #pragma unroll 8
        for (int kk = 0; kk < 32; ++kk) {
            float a = Ash[cur][kk][rbase + lane];
            const float* tr = trb + (size_t)kk * NDIM;   // wave-uniform
            #pragma unroll
            for (int cc = 0; cc < 32; ++cc) acc[cc] = fmaf(a, tr[cc], acc[cc]);
        }

        // write prefetched chunk into the other buffer (nobody reads it now)
        if (c < 3) {
            STORE4(cur ^ 1, p0, 0) STORE4(cur ^ 1, p1, 1)
            STORE4(cur ^ 1, p2, 2) STORE4(cur ^ 1, p3, 3)
        }
        __syncthreads();   // single barrier per chunk
        cur ^= 1;
    }

    // ---- epilogue: out[b][g0 + rbase + lane][cbase + 0..31] ----
    float* op = out + ((size_t)b * OGS + g0 + rbase + lane) * NDIM + cbase;
    #pragma unroll
    for (int c4 = 0; c4 < 8; ++c4) {
        float4 v = make_float4(acc[c4 * 4 + 0], acc[c4 * 4 + 1],
                               acc[c4 * 4 + 2], acc[c4 * 4 + 3]);
        *(float4*)(op + c4 * 4) = v;
    }
}

extern "C" void kernel_launch(void* const* d_in, const int* in_sizes, int n_in,
                              void* d_out, int out_size, void* d_ws, size_t ws_size,
                              hipStream_t stream) {
    const float* x     = (const float*)d_in[0];   // (512, 2048, 64) f32
    const float* trafo = (const float*)d_in[1];   // (128, 64) f32
    float* out         = (float*)d_out;           // (512, 1024, 64) f32
    int* order         = (int*)d_ws;              // 512*2048 ints = 4 MiB

    radix_sort_kernel<<<BATCH, 1024, 0, stream>>>(x, order);
    gather_gemm_kernel<<<BATCH * (OGS / TM), 256, 0, stream>>>(x, trafo, order, out);
}